// Round 1
// baseline (595.330 us; speedup 1.0000x reference)
//
#include <hip/hip_runtime.h>
#include <math.h>

#define HDIM 256
#define NC 15   // value + 4 grad + 10 hess (pairs: 00,01,02,03,11,12,13,22,23,33)

// Propagate (value, grad, hessian) state through one 256x256 tanh layer.
// State for 256 input neurons lives in st[i][0..14]; each lane accumulates
// output neurons j = 4*lane+p. Result (post-tanh chain rule) in ns[4][NC].
__device__ __forceinline__ void hidden_layer(
    const float* __restrict__ W, const float* __restrict__ b,
    const float (*st)[16], int lane, float ns[4][NC])
{
    float acc[4][NC];
#pragma unroll
    for (int p = 0; p < 4; ++p) {
        acc[p][0] = b[4 * lane + p];
#pragma unroll
        for (int c = 1; c < NC; ++c) acc[p][c] = 0.f;
    }
#pragma unroll 2
    for (int i = 0; i < HDIM; ++i) {
        const float4 wv = *reinterpret_cast<const float4*>(W + i * HDIM + 4 * lane);
        float wl[4] = {wv.x, wv.y, wv.z, wv.w};
        const float4 s0 = *reinterpret_cast<const float4*>(&st[i][0]);
        const float4 s1 = *reinterpret_cast<const float4*>(&st[i][4]);
        const float4 s2 = *reinterpret_cast<const float4*>(&st[i][8]);
        const float4 s3 = *reinterpret_cast<const float4*>(&st[i][12]);
        float sv[NC] = {s0.x, s0.y, s0.z, s0.w, s1.x, s1.y, s1.z, s1.w,
                        s2.x, s2.y, s2.z, s2.w, s3.x, s3.y, s3.z};
#pragma unroll
        for (int p = 0; p < 4; ++p)
#pragma unroll
            for (int c = 0; c < NC; ++c)
                acc[p][c] = fmaf(wl[p], sv[c], acc[p][c]);
    }
    // tanh chain rule: v=tanh(a); G = t'*Ga; H = t'*Ha - 2 v t' Ga (x) Ga
#pragma unroll
    for (int p = 0; p < 4; ++p) {
        float v  = tanhf(acc[p][0]);
        float tp = 1.f - v * v;
        float m  = -2.f * v * tp;
        float g0 = acc[p][1], g1 = acc[p][2], g2 = acc[p][3], g3 = acc[p][4];
        ns[p][0] = v;
        ns[p][1] = tp * g0; ns[p][2] = tp * g1; ns[p][3] = tp * g2; ns[p][4] = tp * g3;
        ns[p][5]  = fmaf(tp, acc[p][5],  m * g0 * g0);
        ns[p][6]  = fmaf(tp, acc[p][6],  m * g0 * g1);
        ns[p][7]  = fmaf(tp, acc[p][7],  m * g0 * g2);
        ns[p][8]  = fmaf(tp, acc[p][8],  m * g0 * g3);
        ns[p][9]  = fmaf(tp, acc[p][9],  m * g1 * g1);
        ns[p][10] = fmaf(tp, acc[p][10], m * g1 * g2);
        ns[p][11] = fmaf(tp, acc[p][11], m * g1 * g3);
        ns[p][12] = fmaf(tp, acc[p][12], m * g2 * g2);
        ns[p][13] = fmaf(tp, acc[p][13], m * g2 * g3);
        ns[p][14] = fmaf(tp, acc[p][14], m * g3 * g3);
    }
}

// Kernel 1: one wave (block of 64) per sample. Computes f, grad f, hess f of
// the scalar MLP and writes the 15 values to out[s*16 + 0..14].
__global__ __launch_bounds__(64, 3) void mlp_vgh(
    const float* __restrict__ coords,
    const float* __restrict__ W1, const float* __restrict__ b1,
    const float* __restrict__ W2, const float* __restrict__ b2,
    const float* __restrict__ W3, const float* __restrict__ b3,
    const float* __restrict__ Wo, const float* __restrict__ bo,
    float* __restrict__ out)
{
    __shared__ float st[HDIM][16];   // 16 KB: 15 comps + pad for b128 alignment
    const int s = blockIdx.x;
    const int lane = threadIdx.x;

    const float x0 = coords[s * 4 + 0];
    const float x1 = coords[s * 4 + 1];
    const float x2 = coords[s * 4 + 2];
    const float x3 = coords[s * 4 + 3];

    // ---- layer 1: u = x@W1 + b1; Ga[k] = W1[k,j]; Ha = 0
#pragma unroll
    for (int p = 0; p < 4; ++p) {
        int j = 4 * lane + p;
        float w0 = W1[0 * HDIM + j], w1 = W1[1 * HDIM + j];
        float w2 = W1[2 * HDIM + j], w3 = W1[3 * HDIM + j];
        float a = b1[j];
        a = fmaf(x0, w0, a); a = fmaf(x1, w1, a);
        a = fmaf(x2, w2, a); a = fmaf(x3, w3, a);
        float v  = tanhf(a);
        float tp = 1.f - v * v;
        float m  = -2.f * v * tp;
        st[j][0] = v;
        st[j][1] = tp * w0; st[j][2] = tp * w1; st[j][3] = tp * w2; st[j][4] = tp * w3;
        st[j][5]  = m * w0 * w0; st[j][6]  = m * w0 * w1; st[j][7]  = m * w0 * w2;
        st[j][8]  = m * w0 * w3; st[j][9]  = m * w1 * w1; st[j][10] = m * w1 * w2;
        st[j][11] = m * w1 * w3; st[j][12] = m * w2 * w2; st[j][13] = m * w2 * w3;
        st[j][14] = m * w3 * w3; st[j][15] = 0.f;
    }
    __syncthreads();

    float ns[4][NC];
    hidden_layer(W2, b2, st, lane, ns);
    __syncthreads();
#pragma unroll
    for (int p = 0; p < 4; ++p) {
#pragma unroll
        for (int c = 0; c < NC; ++c) st[4 * lane + p][c] = ns[p][c];
    }
    __syncthreads();
    hidden_layer(W3, b3, st, lane, ns);

    // ---- output layer: 15 length-256 dot products with Wo
    float part[NC];
#pragma unroll
    for (int c = 0; c < NC; ++c) part[c] = 0.f;
#pragma unroll
    for (int p = 0; p < 4; ++p) {
        float wo = Wo[4 * lane + p];
#pragma unroll
        for (int c = 0; c < NC; ++c) part[c] = fmaf(wo, ns[p][c], part[c]);
    }
#pragma unroll
    for (int off = 32; off > 0; off >>= 1) {
#pragma unroll
        for (int c = 0; c < NC; ++c) part[c] += __shfl_xor(part[c], off, 64);
    }
    if (lane == 0) {
        part[0] += bo[0];
#pragma unroll
        for (int c = 0; c < NC; ++c) out[s * 16 + c] = part[c];
    }
}

// Kernel 2: one thread per sample. Reads f, Gf, Hf from out[s*16+0..14],
// builds the diagonal metric derivatives analytically, does the full
// Christoffel/Riemann/Ricci/Einstein algebra, writes G^{ab} (16 floats).
__global__ void einstein_k(const float* __restrict__ coords, float* out, int B)
{
    int s = blockIdx.x * blockDim.x + threadIdx.x;
    if (s >= B) return;

    float f = out[s * 16 + 0];
    float Gf[4];
#pragma unroll
    for (int k = 0; k < 4; ++k) Gf[k] = out[s * 16 + 1 + k];
    float Hs[10];
#pragma unroll
    for (int q = 0; q < 10; ++q) Hs[q] = out[s * 16 + 5 + q];
    float Hf[4][4];
    {
        int q = 0;
#pragma unroll
        for (int k = 0; k < 4; ++k)
#pragma unroll
            for (int l = k; l < 4; ++l) { Hf[k][l] = Hs[q]; Hf[l][k] = Hs[q]; ++q; }
    }

    float r  = coords[s * 4 + 1];
    float th = coords[s * 4 + 2];
    float sn = sinf(th), cs = cosf(th);
    float E  = expf(f);

    float gd[4] = {-1.f, E, r * r, r * r * sn * sn};
    float gi[4];
#pragma unroll
    for (int a = 0; a < 4; ++a) gi[a] = 1.f / gd[a];

    // dgv[a][k] = d_k g_aa ; ddg[a][k][l] = d_k d_l g_aa
    float dgv[4][4];
    float ddg[4][4][4];
#pragma unroll
    for (int a = 0; a < 4; ++a)
#pragma unroll
        for (int k = 0; k < 4; ++k) {
            dgv[a][k] = 0.f;
#pragma unroll
            for (int l = 0; l < 4; ++l) ddg[a][k][l] = 0.f;
        }
#pragma unroll
    for (int k = 0; k < 4; ++k) dgv[1][k] = E * Gf[k];
    dgv[2][1] = 2.f * r;
    dgv[3][1] = 2.f * r * sn * sn;
    dgv[3][2] = 2.f * r * r * sn * cs;
#pragma unroll
    for (int k = 0; k < 4; ++k)
#pragma unroll
        for (int l = 0; l < 4; ++l)
            ddg[1][k][l] = E * fmaf(Gf[k], Gf[l], Hf[k][l]);
    ddg[2][1][1] = 2.f;
    ddg[3][1][1] = 2.f * sn * sn;
    ddg[3][1][2] = 4.f * r * sn * cs;
    ddg[3][2][1] = 4.f * r * sn * cs;
    ddg[3][2][2] = 2.f * r * r * (cs * cs - sn * sn);

    auto SYMF = [&](int a, int i, int j) -> float {
        float sy = 0.f;
        if (a == i) sy += dgv[a][j];
        if (a == j) sy += dgv[a][i];
        if (i == j) sy -= dgv[i][a];
        return sy;
    };
    // D[a,i,j,k] = d_k Gamma^a_{ij}
    auto DF = [&](int a, int i, int j, int k) -> float {
        float ds = 0.f;
        if (a == i) ds += ddg[a][j][k];
        if (a == j) ds += ddg[a][i][k];
        if (i == j) ds -= ddg[i][a][k];
        return 0.5f * (gi[a] * ds - gi[a] * gi[a] * dgv[a][k] * SYMF(a, i, j));
    };

    float Gm[4][4][4];
#pragma unroll
    for (int a = 0; a < 4; ++a)
#pragma unroll
        for (int i = 0; i < 4; ++i)
#pragma unroll
            for (int j = 0; j < 4; ++j)
                Gm[a][i][j] = 0.5f * gi[a] * SYMF(a, i, j);

    // ricci[b][d] = sum_a [ d_a G^a_{db} - d_d G^a_{ab}
    //                      + sum_e (G^a_{ae} G^e_{db} - G^a_{de} G^e_{ab}) ]
    float ric[4][4];
#pragma unroll
    for (int b = 0; b < 4; ++b)
#pragma unroll
        for (int d = 0; d < 4; ++d) {
            float sum = 0.f;
#pragma unroll
            for (int a = 0; a < 4; ++a) {
                sum += DF(a, d, b, a) - DF(a, a, b, d);
#pragma unroll
                for (int e = 0; e < 4; ++e)
                    sum += Gm[a][a][e] * Gm[e][d][b] - Gm[a][d][e] * Gm[e][a][b];
            }
            ric[b][d] = sum;
        }

    float Rs = 0.f;
#pragma unroll
    for (int b = 0; b < 4; ++b) Rs += gi[b] * ric[b][b];

#pragma unroll
    for (int a = 0; a < 4; ++a)
#pragma unroll
        for (int b = 0; b < 4; ++b) {
            float v = gi[a] * gi[b] * ric[a][b];
            if (a == b) v -= 0.5f * gi[a] * Rs;
            out[s * 16 + a * 4 + b] = v;
        }
}

extern "C" void kernel_launch(void* const* d_in, const int* in_sizes, int n_in,
                              void* d_out, int out_size, void* d_ws, size_t ws_size,
                              hipStream_t stream) {
    const float* coords = (const float*)d_in[0];
    const float* W1 = (const float*)d_in[1];
    const float* b1 = (const float*)d_in[2];
    const float* W2 = (const float*)d_in[3];
    const float* b2 = (const float*)d_in[4];
    const float* W3 = (const float*)d_in[5];
    const float* b3 = (const float*)d_in[6];
    const float* Wo = (const float*)d_in[7];
    const float* bo = (const float*)d_in[8];
    float* out = (float*)d_out;
    const int B = in_sizes[0] / 4;

    mlp_vgh<<<B, 64, 0, stream>>>(coords, W1, b1, W2, b2, W3, b3, Wo, bo, out);
    einstein_k<<<(B + 255) / 256, 256, 0, stream>>>(coords, out, B);
}

// Round 2
// 309.735 us; speedup vs baseline: 1.9221x; 1.9221x over previous
//
#include <hip/hip_runtime.h>
#include <math.h>

typedef _Float16 half8 __attribute__((ext_vector_type(8)));
typedef _Float16 half4h __attribute__((ext_vector_type(4)));
typedef float floatx4 __attribute__((ext_vector_type(4)));

#define HDIM 256
#define NC 15        // value + 4 grad + 10 hess
#define SPB 16       // samples per block
#define KH 128       // K streamed in two halves
#define STRIDE 136   // f16 per LDS row: 128 + 8 pad (272B, 16B-aligned rows)
#define MROWS 240    // 15 comps * 16 samples

// ---------------------------------------------------------------------------
// Kernel 1: MFMA forward-mode (value,grad,hess) propagation.
// Block = 512 thr (8 waves), 16 samples. M=240 rows (m = c*16 + sl), N=256,
// K=256 per hidden layer. K streamed in halves through one 65,280B LDS buf.
// Wave w owns n-tiles {2w, 2w+1} (32 neurons); all 15 m-tiles per wave, so
// each lane ends up holding all 15 comps of 4 samples -> chain rule in regs.
// ---------------------------------------------------------------------------
__global__ __launch_bounds__(512, 1) void mlp_vgh_mfma(
    const float* __restrict__ coords,
    const float* __restrict__ W1, const float* __restrict__ b1,
    const float* __restrict__ W2, const float* __restrict__ b2,
    const float* __restrict__ W3, const float* __restrict__ b3,
    const float* __restrict__ Wo, const float* __restrict__ bo,
    float* __restrict__ out, int B)
{
    __shared__ _Float16 st[MROWS * STRIDE];   // 65,280 B

    const int tid  = threadIdx.x;
    const int w    = tid >> 6;       // wave 0..7
    const int lane = tid & 63;
    const int col  = lane & 15;      // MFMA n / A-row selector
    const int q    = lane >> 4;      // quad
    const int s0   = blockIdx.x * SPB;

    floatx4 acc[NC][2];
    half4h  held[NC][2];             // post-tanh layer-2 state (f16 packed)

    // ---- layer-1 producer: thread -> sample sl = tid&15, 4 neurons ----
    auto produce1 = [&](int half) {
        const int sl = tid & 15;
        const int jg = tid >> 4;                 // 0..31
        int ss = s0 + sl; if (ss >= B) ss = B - 1;
        float x0 = coords[ss * 4 + 0];
        float x1 = coords[ss * 4 + 1];
        float x2 = coords[ss * 4 + 2];
        float x3 = coords[ss * 4 + 3];
#pragma unroll
        for (int jj = 0; jj < 4; ++jj) {
            int jl = jg * 4 + jj;                // 0..127
            int j  = half * KH + jl;
            float w0 = W1[0 * HDIM + j], w1 = W1[1 * HDIM + j];
            float w2v = W1[2 * HDIM + j], w3v = W1[3 * HDIM + j];
            float a = b1[j];
            a = fmaf(x0, w0, a); a = fmaf(x1, w1, a);
            a = fmaf(x2, w2v, a); a = fmaf(x3, w3v, a);
            float v = tanhf(a), tp = 1.f - v * v, m2 = -2.f * v * tp;
            float g[4] = {w0, w1, w2v, w3v};
            float o[NC];
            o[0] = v; o[1] = tp * w0; o[2] = tp * w1; o[3] = tp * w2v; o[4] = tp * w3v;
            int idx = 5;
#pragma unroll
            for (int aa = 0; aa < 4; ++aa)
#pragma unroll
                for (int bb = aa; bb < 4; ++bb) { o[idx] = m2 * g[aa] * g[bb]; ++idx; }
#pragma unroll
            for (int c = 0; c < NC; ++c)
                st[(c * 16 + sl) * STRIDE + jl] = (_Float16)o[c];
        }
    };

    auto init_acc = [&](const float* __restrict__ b) {
        float bj0 = b[(w * 2 + 0) * 16 + col];
        float bj1 = b[(w * 2 + 1) * 16 + col];
#pragma unroll
        for (int mt = 0; mt < NC; ++mt)
#pragma unroll
            for (int nt = 0; nt < 2; ++nt)
#pragma unroll
                for (int r = 0; r < 4; ++r) acc[mt][nt][r] = 0.f;
#pragma unroll
        for (int r = 0; r < 4; ++r) { acc[0][0][r] = bj0; acc[0][1][r] = bj1; }
    };

    // GEMM over one K-half: A = st (f16, LDS), B = W rows [half*128, +128)
    auto gemm_half = [&](const float* __restrict__ W, int half) {
        const int j0 = (w * 2 + 0) * 16 + col;
        const int j1 = (w * 2 + 1) * 16 + col;
#pragma unroll
        for (int ks = 0; ks < 4; ++ks) {
            const int kg = half * KH + ks * 32 + q * 8;
            half8 bf0, bf1;
#pragma unroll
            for (int i = 0; i < 8; ++i) {
                bf0[i] = (_Float16)W[(kg + i) * HDIM + j0];
                bf1[i] = (_Float16)W[(kg + i) * HDIM + j1];
            }
#pragma unroll
            for (int mt = 0; mt < NC; ++mt) {
                half8 af = *(const half8*)&st[(mt * 16 + col) * STRIDE + ks * 32 + q * 8];
                acc[mt][0] = __builtin_amdgcn_mfma_f32_16x16x32_f16(af, bf0, acc[mt][0], 0, 0, 0);
                acc[mt][1] = __builtin_amdgcn_mfma_f32_16x16x32_f16(af, bf1, acc[mt][1], 0, 0, 0);
            }
        }
    };

    // tanh chain rule on acc -> held (f16). Lane holds comps c for samples
    // sl = q*4 + r, neuron j = (w*2+nt)*16 + col  (C/D: row=q*4+r, col=lane&15)
    auto transform = [&]() {
#pragma unroll
        for (int nt = 0; nt < 2; ++nt)
#pragma unroll
            for (int r = 0; r < 4; ++r) {
                float pre[NC];
#pragma unroll
                for (int c = 0; c < NC; ++c) pre[c] = acc[c][nt][r];
                float v = tanhf(pre[0]), tp = 1.f - v * v, m2 = -2.f * v * tp;
                float g[4] = {pre[1], pre[2], pre[3], pre[4]};
                float o[NC];
                o[0] = v;
#pragma unroll
                for (int k = 0; k < 4; ++k) o[1 + k] = tp * g[k];
                int idx = 5;
#pragma unroll
                for (int aa = 0; aa < 4; ++aa)
#pragma unroll
                    for (int bb = aa; bb < 4; ++bb) {
                        o[idx] = fmaf(tp, pre[idx], m2 * g[aa] * g[bb]); ++idx;
                    }
#pragma unroll
                for (int c = 0; c < NC; ++c) held[c][nt][r] = (_Float16)o[c];
            }
    };

    // store held into st as next-layer A state: row m = c*16 + (q*4+r), col j
    auto store_half = [&](int half) {
#pragma unroll
        for (int nt = 0; nt < 2; ++nt) {
            int jl = (w * 2 + nt) * 16 + col - half * KH;   // in [0,128)
#pragma unroll
            for (int c = 0; c < NC; ++c)
#pragma unroll
                for (int r = 0; r < 4; ++r)
                    st[(c * 16 + q * 4 + r) * STRIDE + jl] = held[c][nt][r];
        }
    };

    // ================= pipeline =================
    produce1(0);
    __syncthreads();
    init_acc(b2);
    gemm_half(W2, 0);
    __syncthreads();
    produce1(1);
    __syncthreads();
    gemm_half(W2, 1);
    __syncthreads();                  // st1 fully consumed
    transform();                      // held = layer-2 state
    if (w < 4) store_half(0);         // waves owning j<128
    __syncthreads();
    init_acc(b3);
    gemm_half(W3, 0);
    __syncthreads();
    if (w >= 4) store_half(1);
    __syncthreads();
    gemm_half(W3, 1);

    // ---- layer-3 tanh chain + output dot with Wo ----
    float p[NC][4];
    {
        float wo0 = Wo[(w * 2 + 0) * 16 + col];
        float wo1 = Wo[(w * 2 + 1) * 16 + col];
#pragma unroll
        for (int r = 0; r < 4; ++r) {
            float on[2][NC];
#pragma unroll
            for (int nt = 0; nt < 2; ++nt) {
                float pre[NC];
#pragma unroll
                for (int c = 0; c < NC; ++c) pre[c] = acc[c][nt][r];
                float v = tanhf(pre[0]), tp = 1.f - v * v, m2 = -2.f * v * tp;
                float g[4] = {pre[1], pre[2], pre[3], pre[4]};
                on[nt][0] = v;
#pragma unroll
                for (int k = 0; k < 4; ++k) on[nt][1 + k] = tp * g[k];
                int idx = 5;
#pragma unroll
                for (int aa = 0; aa < 4; ++aa)
#pragma unroll
                    for (int bb = aa; bb < 4; ++bb) {
                        on[nt][idx] = fmaf(tp, pre[idx], m2 * g[aa] * g[bb]); ++idx;
                    }
            }
#pragma unroll
            for (int c = 0; c < NC; ++c)
                p[c][r] = fmaf(wo0, on[0][c], wo1 * on[1][c]);
        }
    }
    // reduce over the 16 col-lanes (neurons within wave)
#pragma unroll
    for (int mask = 1; mask < 16; mask <<= 1)
#pragma unroll
        for (int c = 0; c < NC; ++c)
#pragma unroll
            for (int r = 0; r < 4; ++r)
                p[c][r] += __shfl_xor(p[c][r], mask, 64);

    __syncthreads();                  // st reads done; safe to alias
    float* part = (float*)st;         // part[w][c][sl] : 8*240 f32 = 7680 B
    if (col == 0) {
#pragma unroll
        for (int c = 0; c < NC; ++c)
#pragma unroll
            for (int r = 0; r < 4; ++r)
                part[w * 240 + c * 16 + q * 4 + r] = p[c][r];
    }
    __syncthreads();
    if (tid < 240) {
        float v = 0.f;
#pragma unroll
        for (int ww = 0; ww < 8; ++ww) v += part[ww * 240 + tid];
        int c = tid >> 4, sl = tid & 15;
        if (c == 0) v += bo[0];
        if (s0 + sl < B) out[(s0 + sl) * 16 + c] = v;
    }
}

// ---------------------------------------------------------------------------
// Kernel 2: per-sample analytic Einstein tensor from (f, grad f, hess f).
// ---------------------------------------------------------------------------
__global__ void einstein_k(const float* __restrict__ coords, float* out, int B)
{
    int s = blockIdx.x * blockDim.x + threadIdx.x;
    if (s >= B) return;

    float f = out[s * 16 + 0];
    float Gf[4];
#pragma unroll
    for (int k = 0; k < 4; ++k) Gf[k] = out[s * 16 + 1 + k];
    float Hs[10];
#pragma unroll
    for (int qq = 0; qq < 10; ++qq) Hs[qq] = out[s * 16 + 5 + qq];
    float Hf[4][4];
    {
        int qq = 0;
#pragma unroll
        for (int k = 0; k < 4; ++k)
#pragma unroll
            for (int l = k; l < 4; ++l) { Hf[k][l] = Hs[qq]; Hf[l][k] = Hs[qq]; ++qq; }
    }

    float r  = coords[s * 4 + 1];
    float th = coords[s * 4 + 2];
    float sn = sinf(th), cs = cosf(th);
    float E  = expf(f);

    float gd[4] = {-1.f, E, r * r, r * r * sn * sn};
    float gi[4];
#pragma unroll
    for (int a = 0; a < 4; ++a) gi[a] = 1.f / gd[a];

    float dgv[4][4];
    float ddg[4][4][4];
#pragma unroll
    for (int a = 0; a < 4; ++a)
#pragma unroll
        for (int k = 0; k < 4; ++k) {
            dgv[a][k] = 0.f;
#pragma unroll
            for (int l = 0; l < 4; ++l) ddg[a][k][l] = 0.f;
        }
#pragma unroll
    for (int k = 0; k < 4; ++k) dgv[1][k] = E * Gf[k];
    dgv[2][1] = 2.f * r;
    dgv[3][1] = 2.f * r * sn * sn;
    dgv[3][2] = 2.f * r * r * sn * cs;
#pragma unroll
    for (int k = 0; k < 4; ++k)
#pragma unroll
        for (int l = 0; l < 4; ++l)
            ddg[1][k][l] = E * fmaf(Gf[k], Gf[l], Hf[k][l]);
    ddg[2][1][1] = 2.f;
    ddg[3][1][1] = 2.f * sn * sn;
    ddg[3][1][2] = 4.f * r * sn * cs;
    ddg[3][2][1] = 4.f * r * sn * cs;
    ddg[3][2][2] = 2.f * r * r * (cs * cs - sn * sn);

    auto SYMF = [&](int a, int i, int j) -> float {
        float sy = 0.f;
        if (a == i) sy += dgv[a][j];
        if (a == j) sy += dgv[a][i];
        if (i == j) sy -= dgv[i][a];
        return sy;
    };
    auto DF = [&](int a, int i, int j, int k) -> float {
        float ds = 0.f;
        if (a == i) ds += ddg[a][j][k];
        if (a == j) ds += ddg[a][i][k];
        if (i == j) ds -= ddg[i][a][k];
        return 0.5f * (gi[a] * ds - gi[a] * gi[a] * dgv[a][k] * SYMF(a, i, j));
    };

    float Gm[4][4][4];
#pragma unroll
    for (int a = 0; a < 4; ++a)
#pragma unroll
        for (int i = 0; i < 4; ++i)
#pragma unroll
            for (int j = 0; j < 4; ++j)
                Gm[a][i][j] = 0.5f * gi[a] * SYMF(a, i, j);

    float ric[4][4];
#pragma unroll
    for (int b = 0; b < 4; ++b)
#pragma unroll
        for (int d = 0; d < 4; ++d) {
            float sum = 0.f;
#pragma unroll
            for (int a = 0; a < 4; ++a) {
                sum += DF(a, d, b, a) - DF(a, a, b, d);
#pragma unroll
                for (int e = 0; e < 4; ++e)
                    sum += Gm[a][a][e] * Gm[e][d][b] - Gm[a][d][e] * Gm[e][a][b];
            }
            ric[b][d] = sum;
        }

    float Rs = 0.f;
#pragma unroll
    for (int b = 0; b < 4; ++b) Rs += gi[b] * ric[b][b];

#pragma unroll
    for (int a = 0; a < 4; ++a)
#pragma unroll
        for (int b = 0; b < 4; ++b) {
            float v = gi[a] * gi[b] * ric[a][b];
            if (a == b) v -= 0.5f * gi[a] * Rs;
            out[s * 16 + a * 4 + b] = v;
        }
}

extern "C" void kernel_launch(void* const* d_in, const int* in_sizes, int n_in,
                              void* d_out, int out_size, void* d_ws, size_t ws_size,
                              hipStream_t stream) {
    const float* coords = (const float*)d_in[0];
    const float* W1 = (const float*)d_in[1];
    const float* b1 = (const float*)d_in[2];
    const float* W2 = (const float*)d_in[3];
    const float* b2 = (const float*)d_in[4];
    const float* W3 = (const float*)d_in[5];
    const float* b3 = (const float*)d_in[6];
    const float* Wo = (const float*)d_in[7];
    const float* bo = (const float*)d_in[8];
    float* out = (float*)d_out;
    const int B = in_sizes[0] / 4;

    const int nblocks = (B + SPB - 1) / SPB;
    mlp_vgh_mfma<<<nblocks, 512, 0, stream>>>(coords, W1, b1, W2, b2, W3, b3,
                                              Wo, bo, out, B);
    einstein_k<<<(B + 255) / 256, 256, 0, stream>>>(coords, out, B);
}

// Round 3
// 223.002 us; speedup vs baseline: 2.6696x; 1.3889x over previous
//
#include <hip/hip_runtime.h>
#include <math.h>

typedef _Float16 half8 __attribute__((ext_vector_type(8)));
typedef _Float16 half2h __attribute__((ext_vector_type(2)));
typedef float floatx4 __attribute__((ext_vector_type(4)));

#define HDIM 256
#define NC 15        // value + 4 grad + 10 hess
#define SPB 16       // samples per block
#define KH 128       // K streamed in two halves
#define STRIDE 136   // f16 per LDS row: 128 + 8 pad
#define MROWS 240    // 15 comps * 16 samples

// ---------------------------------------------------------------------------
// Kernel 1: MFMA forward-mode (value,grad,hess) propagation.
// Block = 1024 thr (16 waves), 16 samples. M=240 (m = c*16 + sl), N=256,
// K=256 per layer, K streamed in halves through one 65,280B LDS buffer.
// Wave w owns n-tile w (16 neurons) -> acc[15] = 60 AGPRs only (no spill).
// C/D layout (16x16x32): row = q*4+r = sample, col = lane&15 = neuron,
// m-tile index = comp -> all 15 comps of a sample live in one lane.
// ---------------------------------------------------------------------------
__global__ __launch_bounds__(1024, 1) void mlp_vgh_mfma(
    const float* __restrict__ coords,
    const float* __restrict__ W1, const float* __restrict__ b1,
    const float* __restrict__ W2, const float* __restrict__ b2,
    const float* __restrict__ W3, const float* __restrict__ b3,
    const float* __restrict__ Wo, const float* __restrict__ bo,
    float* __restrict__ out, int B)
{
    __shared__ _Float16 st[MROWS * STRIDE];   // 65,280 B

    const int tid  = threadIdx.x;
    const int w    = tid >> 6;       // wave 0..15
    const int lane = tid & 63;
    const int col  = lane & 15;
    const int q    = lane >> 4;
    const int s0   = blockIdx.x * SPB;
    const int j    = w * 16 + col;   // neuron this lane accumulates

    floatx4 acc[NC];                 // 60 AGPRs
    _Float16 hold[NC * 4];           // 30 VGPRs, transient

    // ---- layer-1 producer: thread -> sample tid&15, col pair 2*(tid>>4) ----
    auto produce1 = [&](int half) {
        const int sl = tid & 15;
        const int cp = tid >> 4;                 // 0..63
        int ss = s0 + sl; if (ss >= B) ss = B - 1;
        const float x0 = coords[ss * 4 + 0];
        const float x1 = coords[ss * 4 + 1];
        const float x2 = coords[ss * 4 + 2];
        const float x3 = coords[ss * 4 + 3];
        const int jl0 = 2 * cp;
        const int jg  = half * KH + jl0;
        float2 wr0 = *(const float2*)&W1[0 * HDIM + jg];
        float2 wr1 = *(const float2*)&W1[1 * HDIM + jg];
        float2 wr2 = *(const float2*)&W1[2 * HDIM + jg];
        float2 wr3 = *(const float2*)&W1[3 * HDIM + jg];
        float2 bb  = *(const float2*)&b1[jg];
        float oA[NC], oB[NC];
#pragma unroll
        for (int t = 0; t < 2; ++t) {
            float w0 = t ? wr0.y : wr0.x, w1 = t ? wr1.y : wr1.x;
            float w2v = t ? wr2.y : wr2.x, w3v = t ? wr3.y : wr3.x;
            float a = t ? bb.y : bb.x;
            a = fmaf(x0, w0, a); a = fmaf(x1, w1, a);
            a = fmaf(x2, w2v, a); a = fmaf(x3, w3v, a);
            float v = tanhf(a), tp = 1.f - v * v, m2 = -2.f * v * tp;
            float g[4] = {w0, w1, w2v, w3v};
            float* o = t ? oB : oA;
            o[0] = v; o[1] = tp * w0; o[2] = tp * w1; o[3] = tp * w2v; o[4] = tp * w3v;
            int idx = 5;
#pragma unroll
            for (int aa = 0; aa < 4; ++aa)
#pragma unroll
                for (int bb2 = aa; bb2 < 4; ++bb2) { o[idx] = m2 * g[aa] * g[bb2]; ++idx; }
        }
#pragma unroll
        for (int c = 0; c < NC; ++c) {
            half2h pk; pk[0] = (_Float16)oA[c]; pk[1] = (_Float16)oB[c];
            *(half2h*)&st[(c * 16 + sl) * STRIDE + jl0] = pk;
        }
    };

    auto init_acc = [&](const float* __restrict__ b) {
        float bj = b[j];
#pragma unroll
        for (int c = 0; c < NC; ++c)
#pragma unroll
            for (int r = 0; r < 4; ++r) acc[c][r] = 0.f;
#pragma unroll
        for (int r = 0; r < 4; ++r) acc[0][r] = bj;
    };

    // GEMM over one K-half: A = st (f16 LDS), B = W rows [half*128, +128)
    auto gemm_half = [&](const float* __restrict__ W, int half) {
#pragma unroll
        for (int ks = 0; ks < 4; ++ks) {
            const int kg = half * KH + ks * 32 + q * 8;
            half8 bf;
#pragma unroll
            for (int i = 0; i < 8; ++i) bf[i] = (_Float16)W[(kg + i) * HDIM + j];
#pragma unroll
            for (int mt = 0; mt < NC; ++mt) {
                half8 af = *(const half8*)&st[(mt * 16 + col) * STRIDE + ks * 32 + q * 8];
                acc[mt] = __builtin_amdgcn_mfma_f32_16x16x32_f16(af, bf, acc[mt], 0, 0, 0);
            }
        }
    };

    // tanh chain rule on acc -> hold (f16)
    auto transform_hold = [&]() {
#pragma unroll
        for (int r = 0; r < 4; ++r) {
            float pre[NC];
#pragma unroll
            for (int c = 0; c < NC; ++c) pre[c] = acc[c][r];
            float v = tanhf(pre[0]), tp = 1.f - v * v, m2 = -2.f * v * tp;
            float g[4] = {pre[1], pre[2], pre[3], pre[4]};
            hold[0 * 4 + r] = (_Float16)v;
#pragma unroll
            for (int k = 0; k < 4; ++k) hold[(1 + k) * 4 + r] = (_Float16)(tp * g[k]);
            int idx = 5;
#pragma unroll
            for (int aa = 0; aa < 4; ++aa)
#pragma unroll
                for (int bb2 = aa; bb2 < 4; ++bb2) {
                    hold[idx * 4 + r] = (_Float16)fmaf(tp, pre[idx], m2 * g[aa] * g[bb2]);
                    ++idx;
                }
        }
    };

    auto store_hold = [&](int half) {
        const int jl = j - half * KH;            // in [0,128)
#pragma unroll
        for (int c = 0; c < NC; ++c)
#pragma unroll
            for (int r = 0; r < 4; ++r)
                st[(c * 16 + q * 4 + r) * STRIDE + jl] = hold[c * 4 + r];
    };

    // ================= pipeline =================
    produce1(0);
    __syncthreads();
    init_acc(b2);
    gemm_half(W2, 0);
    __syncthreads();
    produce1(1);
    __syncthreads();
    gemm_half(W2, 1);
    __syncthreads();                  // layer-1 state fully consumed
    transform_hold();                 // layer-2 state (f16, regs)
    if (w < 8) store_hold(0);         // waves owning j<128
    __syncthreads();
    init_acc(b3);
    gemm_half(W3, 0);
    __syncthreads();
    if (w >= 8) store_hold(1);
    __syncthreads();
    gemm_half(W3, 1);

    // ---- layer-3 tanh chain + output dot with Wo ----
    float p[NC][4];
    {
        float wo = Wo[j];
#pragma unroll
        for (int r = 0; r < 4; ++r) {
            float pre[NC];
#pragma unroll
            for (int c = 0; c < NC; ++c) pre[c] = acc[c][r];
            float v = tanhf(pre[0]), tp = 1.f - v * v, m2 = -2.f * v * tp;
            float g[4] = {pre[1], pre[2], pre[3], pre[4]};
            p[0][r] = wo * v;
#pragma unroll
            for (int k = 0; k < 4; ++k) p[1 + k][r] = wo * tp * g[k];
            int idx = 5;
#pragma unroll
            for (int aa = 0; aa < 4; ++aa)
#pragma unroll
                for (int bb2 = aa; bb2 < 4; ++bb2) {
                    p[idx][r] = wo * fmaf(tp, pre[idx], m2 * g[aa] * g[bb2]);
                    ++idx;
                }
        }
    }
    // reduce over the 16 col-lanes (neurons within wave)
#pragma unroll
    for (int mask = 1; mask < 16; mask <<= 1)
#pragma unroll
        for (int c = 0; c < NC; ++c)
#pragma unroll
            for (int r = 0; r < 4; ++r)
                p[c][r] += __shfl_xor(p[c][r], mask, 64);

    __syncthreads();                  // all st reads done; safe to alias
    float* part = (float*)st;         // part[w][c][sl]: 16*240 f32 = 15,360 B
    if (col == 0) {
#pragma unroll
        for (int c = 0; c < NC; ++c)
#pragma unroll
            for (int r = 0; r < 4; ++r)
                part[w * MROWS + c * 16 + q * 4 + r] = p[c][r];
    }
    __syncthreads();
    if (tid < MROWS) {
        float v = 0.f;
#pragma unroll
        for (int ww = 0; ww < 16; ++ww) v += part[ww * MROWS + tid];
        int c = tid >> 4, sl = tid & 15;
        if (c == 0) v += bo[0];
        if (s0 + sl < B) out[(s0 + sl) * 16 + c] = v;
    }
}

// ---------------------------------------------------------------------------
// Kernel 2: per-sample analytic Einstein tensor from (f, grad f, hess f).
// ---------------------------------------------------------------------------
__global__ __launch_bounds__(64) void einstein_k(
    const float* __restrict__ coords, float* out, int B)
{
    int s = blockIdx.x * blockDim.x + threadIdx.x;
    if (s >= B) return;

    float f = out[s * 16 + 0];
    float Gf[4];
#pragma unroll
    for (int k = 0; k < 4; ++k) Gf[k] = out[s * 16 + 1 + k];
    float Hs[10];
#pragma unroll
    for (int qq = 0; qq < 10; ++qq) Hs[qq] = out[s * 16 + 5 + qq];
    float Hf[4][4];
    {
        int qq = 0;
#pragma unroll
        for (int k = 0; k < 4; ++k)
#pragma unroll
            for (int l = k; l < 4; ++l) { Hf[k][l] = Hs[qq]; Hf[l][k] = Hs[qq]; ++qq; }
    }

    float r  = coords[s * 4 + 1];
    float th = coords[s * 4 + 2];
    float sn = sinf(th), cs = cosf(th);
    float E  = expf(f);

    float gd[4] = {-1.f, E, r * r, r * r * sn * sn};
    float gi[4];
#pragma unroll
    for (int a = 0; a < 4; ++a) gi[a] = 1.f / gd[a];

    float dgv[4][4];
    float ddg[4][4][4];
#pragma unroll
    for (int a = 0; a < 4; ++a)
#pragma unroll
        for (int k = 0; k < 4; ++k) {
            dgv[a][k] = 0.f;
#pragma unroll
            for (int l = 0; l < 4; ++l) ddg[a][k][l] = 0.f;
        }
#pragma unroll
    for (int k = 0; k < 4; ++k) dgv[1][k] = E * Gf[k];
    dgv[2][1] = 2.f * r;
    dgv[3][1] = 2.f * r * sn * sn;
    dgv[3][2] = 2.f * r * r * sn * cs;
#pragma unroll
    for (int k = 0; k < 4; ++k)
#pragma unroll
        for (int l = 0; l < 4; ++l)
            ddg[1][k][l] = E * fmaf(Gf[k], Gf[l], Hf[k][l]);
    ddg[2][1][1] = 2.f;
    ddg[3][1][1] = 2.f * sn * sn;
    ddg[3][1][2] = 4.f * r * sn * cs;
    ddg[3][2][1] = 4.f * r * sn * cs;
    ddg[3][2][2] = 2.f * r * r * (cs * cs - sn * sn);

    auto SYMF = [&](int a, int i, int jx) -> float {
        float sy = 0.f;
        if (a == i)  sy += dgv[a][jx];
        if (a == jx) sy += dgv[a][i];
        if (i == jx) sy -= dgv[i][a];
        return sy;
    };
    auto DF = [&](int a, int i, int jx, int k) -> float {
        float ds = 0.f;
        if (a == i)  ds += ddg[a][jx][k];
        if (a == jx) ds += ddg[a][i][k];
        if (i == jx) ds -= ddg[i][a][k];
        return 0.5f * (gi[a] * ds - gi[a] * gi[a] * dgv[a][k] * SYMF(a, i, jx));
    };

    float Gm[4][4][4];
#pragma unroll
    for (int a = 0; a < 4; ++a)
#pragma unroll
        for (int i = 0; i < 4; ++i)
#pragma unroll
            for (int jx = 0; jx < 4; ++jx)
                Gm[a][i][jx] = 0.5f * gi[a] * SYMF(a, i, jx);

    float ric[4][4];
#pragma unroll
    for (int b = 0; b < 4; ++b)
#pragma unroll
        for (int d = 0; d < 4; ++d) {
            float sum = 0.f;
#pragma unroll
            for (int a = 0; a < 4; ++a) {
                sum += DF(a, d, b, a) - DF(a, a, b, d);
#pragma unroll
                for (int e = 0; e < 4; ++e)
                    sum += Gm[a][a][e] * Gm[e][d][b] - Gm[a][d][e] * Gm[e][a][b];
            }
            ric[b][d] = sum;
        }

    float Rs = 0.f;
#pragma unroll
    for (int b = 0; b < 4; ++b) Rs += gi[b] * ric[b][b];

#pragma unroll
    for (int a = 0; a < 4; ++a)
#pragma unroll
        for (int b = 0; b < 4; ++b) {
            float v = gi[a] * gi[b] * ric[a][b];
            if (a == b) v -= 0.5f * gi[a] * Rs;
            out[s * 16 + a * 4 + b] = v;
        }
}

extern "C" void kernel_launch(void* const* d_in, const int* in_sizes, int n_in,
                              void* d_out, int out_size, void* d_ws, size_t ws_size,
                              hipStream_t stream) {
    const float* coords = (const float*)d_in[0];
    const float* W1 = (const float*)d_in[1];
    const float* b1 = (const float*)d_in[2];
    const float* W2 = (const float*)d_in[3];
    const float* b2 = (const float*)d_in[4];
    const float* W3 = (const float*)d_in[5];
    const float* b3 = (const float*)d_in[6];
    const float* Wo = (const float*)d_in[7];
    const float* bo = (const float*)d_in[8];
    float* out = (float*)d_out;
    const int B = in_sizes[0] / 4;

    const int nblocks = (B + SPB - 1) / SPB;
    mlp_vgh_mfma<<<nblocks, 1024, 0, stream>>>(coords, W1, b1, W2, b2, W3, b3,
                                               Wo, bo, out, B);
    einstein_k<<<(B + 63) / 64, 64, 0, stream>>>(coords, out, B);
}

// Round 4
// 191.655 us; speedup vs baseline: 3.1063x; 1.1636x over previous
//
#include <hip/hip_runtime.h>
#include <math.h>

typedef _Float16 half8 __attribute__((ext_vector_type(8)));
typedef _Float16 half2h __attribute__((ext_vector_type(2)));
typedef float floatx4 __attribute__((ext_vector_type(4)));

#define HDIM 256
#define NC 15        // value + 4 grad + 10 hess (00,01,02,03,11,12,13,22,23,33)
#define SPB 16       // samples per block
#define KH 128       // K streamed in two halves
#define STRIDE 136   // f16 per LDS row: 128 + 8 pad
#define MROWS 240    // 15 comps * 16 samples

// ---------------------------------------------------------------------------
// Per-sample analytic Einstein tensor from (f, grad f, hess f). Runs on one
// lane. All arrays constant-indexed under full unroll -> registers.
// ---------------------------------------------------------------------------
__device__ __forceinline__ void einstein_tail(
    float f, const float* Gf, const float* Hs, float r, float th,
    float* __restrict__ outp)
{
    float Hf[4][4];
    {
        int qq = 0;
#pragma unroll
        for (int k = 0; k < 4; ++k)
#pragma unroll
            for (int l = k; l < 4; ++l) { Hf[k][l] = Hs[qq]; Hf[l][k] = Hs[qq]; ++qq; }
    }
    float sn = sinf(th), cs = cosf(th);
    float E  = expf(f);

    float gd[4] = {-1.f, E, r * r, r * r * sn * sn};
    float gi[4];
#pragma unroll
    for (int a = 0; a < 4; ++a) gi[a] = 1.f / gd[a];

    float dgv[4][4];
    float ddg[4][4][4];
#pragma unroll
    for (int a = 0; a < 4; ++a)
#pragma unroll
        for (int k = 0; k < 4; ++k) {
            dgv[a][k] = 0.f;
#pragma unroll
            for (int l = 0; l < 4; ++l) ddg[a][k][l] = 0.f;
        }
#pragma unroll
    for (int k = 0; k < 4; ++k) dgv[1][k] = E * Gf[k];
    dgv[2][1] = 2.f * r;
    dgv[3][1] = 2.f * r * sn * sn;
    dgv[3][2] = 2.f * r * r * sn * cs;
#pragma unroll
    for (int k = 0; k < 4; ++k)
#pragma unroll
        for (int l = 0; l < 4; ++l)
            ddg[1][k][l] = E * fmaf(Gf[k], Gf[l], Hf[k][l]);
    ddg[2][1][1] = 2.f;
    ddg[3][1][1] = 2.f * sn * sn;
    ddg[3][1][2] = 4.f * r * sn * cs;
    ddg[3][2][1] = 4.f * r * sn * cs;
    ddg[3][2][2] = 2.f * r * r * (cs * cs - sn * sn);

    auto SYMF = [&](int a, int i, int jx) -> float {
        float sy = 0.f;
        if (a == i)  sy += dgv[a][jx];
        if (a == jx) sy += dgv[a][i];
        if (i == jx) sy -= dgv[i][a];
        return sy;
    };
    auto DF = [&](int a, int i, int jx, int k) -> float {
        float ds = 0.f;
        if (a == i)  ds += ddg[a][jx][k];
        if (a == jx) ds += ddg[a][i][k];
        if (i == jx) ds -= ddg[i][a][k];
        return 0.5f * (gi[a] * ds - gi[a] * gi[a] * dgv[a][k] * SYMF(a, i, jx));
    };

    float Gm[4][4][4];
#pragma unroll
    for (int a = 0; a < 4; ++a)
#pragma unroll
        for (int i = 0; i < 4; ++i)
#pragma unroll
            for (int jx = 0; jx < 4; ++jx)
                Gm[a][i][jx] = 0.5f * gi[a] * SYMF(a, i, jx);

    float ric[4][4];
#pragma unroll
    for (int b = 0; b < 4; ++b)
#pragma unroll
        for (int d = 0; d < 4; ++d) {
            float sum = 0.f;
#pragma unroll
            for (int a = 0; a < 4; ++a) {
                sum += DF(a, d, b, a) - DF(a, a, b, d);
#pragma unroll
                for (int e = 0; e < 4; ++e)
                    sum += Gm[a][a][e] * Gm[e][d][b] - Gm[a][d][e] * Gm[e][a][b];
            }
            ric[b][d] = sum;
        }

    float Rs = 0.f;
#pragma unroll
    for (int b = 0; b < 4; ++b) Rs += gi[b] * ric[b][b];

#pragma unroll
    for (int a = 0; a < 4; ++a)
#pragma unroll
        for (int b = 0; b < 4; ++b) {
            float v = gi[a] * gi[b] * ric[a][b];
            if (a == b) v -= 0.5f * gi[a] * Rs;
            outp[a * 4 + b] = v;
        }
}

// ---------------------------------------------------------------------------
// Pack W2,W3 transposed to f16 into ws: Wt[m][j*256+k] = W_m[k*256+j].
// ---------------------------------------------------------------------------
__global__ __launch_bounds__(256) void pack_wt(
    const float* __restrict__ W2, const float* __restrict__ W3,
    _Float16* __restrict__ Wt)
{
    int idx = blockIdx.x * 256 + threadIdx.x;          // 0 .. 131071
    const float* W = (idx < HDIM * HDIM) ? W2 : W3;
    int e  = idx & (HDIM * HDIM - 1);
    int jj = e >> 8, kk = e & 255;
    Wt[idx] = (_Float16)W[kk * HDIM + jj];
}

// ---------------------------------------------------------------------------
// Fused kernel: MFMA forward-mode (value,grad,hess) + Einstein tail.
// Block = 1024 thr (16 waves), 16 samples. M=240 (m=c*16+sl), N=256, K=256
// per layer, K streamed in halves through one 65,280B LDS buffer.
// Wave w owns n-tile w (16 neurons) -> acc[15] = 60 AGPRs (no spill).
// C/D layout (16x16x32): row=q*4+r = sample, col=lane&15 = neuron.
// ---------------------------------------------------------------------------
template <bool TW>
__global__ __launch_bounds__(1024, 1) void mlp_fused(
    const float* __restrict__ coords,
    const float* __restrict__ W1, const float* __restrict__ b1,
    const float* __restrict__ W2, const float* __restrict__ b2,
    const float* __restrict__ W3, const float* __restrict__ b3,
    const float* __restrict__ Wo, const float* __restrict__ bo,
    const _Float16* __restrict__ Wt,   // packed f16 W2^T | W3^T (TW only)
    float* __restrict__ out, int B)
{
    __shared__ __align__(16) _Float16 st[MROWS * STRIDE];   // 65,280 B

    const int tid  = threadIdx.x;
    const int w    = tid >> 6;       // wave 0..15
    const int lane = tid & 63;
    const int col  = lane & 15;
    const int q    = lane >> 4;
    const int s0   = blockIdx.x * SPB;
    const int j    = w * 16 + col;   // neuron this lane accumulates

    floatx4 acc[NC];                 // 60 AGPRs
    _Float16 hold[NC * 4];           // 30 VGPRs, transient

    // ---- layer-1 producer: thread -> sample tid&15, col pair 2*(tid>>4) ----
    auto produce1 = [&](int half) {
        const int sl = tid & 15;
        const int cp = tid >> 4;                 // 0..63
        int ss = s0 + sl; if (ss >= B) ss = B - 1;
        const float x0 = coords[ss * 4 + 0];
        const float x1 = coords[ss * 4 + 1];
        const float x2 = coords[ss * 4 + 2];
        const float x3 = coords[ss * 4 + 3];
        const int jl0 = 2 * cp;
        const int jg  = half * KH + jl0;
        float2 wr0 = *(const float2*)&W1[0 * HDIM + jg];
        float2 wr1 = *(const float2*)&W1[1 * HDIM + jg];
        float2 wr2 = *(const float2*)&W1[2 * HDIM + jg];
        float2 wr3 = *(const float2*)&W1[3 * HDIM + jg];
        float2 bb  = *(const float2*)&b1[jg];
        float o2[2][NC];                         // constant-indexed -> regs
#pragma unroll
        for (int t = 0; t < 2; ++t) {
            float w0 = t ? wr0.y : wr0.x, w1 = t ? wr1.y : wr1.x;
            float w2v = t ? wr2.y : wr2.x, w3v = t ? wr3.y : wr3.x;
            float a = t ? bb.y : bb.x;
            a = fmaf(x0, w0, a); a = fmaf(x1, w1, a);
            a = fmaf(x2, w2v, a); a = fmaf(x3, w3v, a);
            float v = tanhf(a), tp = 1.f - v * v, m2 = -2.f * v * tp;
            float g[4] = {w0, w1, w2v, w3v};
            o2[t][0] = v;
            o2[t][1] = tp * w0; o2[t][2] = tp * w1;
            o2[t][3] = tp * w2v; o2[t][4] = tp * w3v;
            int idx = 5;
#pragma unroll
            for (int aa = 0; aa < 4; ++aa)
#pragma unroll
                for (int bb2 = aa; bb2 < 4; ++bb2) {
                    o2[t][idx] = m2 * g[aa] * g[bb2]; ++idx;
                }
        }
#pragma unroll
        for (int c = 0; c < NC; ++c) {
            half2h pk; pk[0] = (_Float16)o2[0][c]; pk[1] = (_Float16)o2[1][c];
            *(half2h*)&st[(c * 16 + sl) * STRIDE + jl0] = pk;
        }
    };

    auto init_acc = [&](const float* __restrict__ b) {
        float bj = b[j];
#pragma unroll
        for (int c = 0; c < NC; ++c)
#pragma unroll
            for (int r = 0; r < 4; ++r) acc[c][r] = 0.f;
#pragma unroll
        for (int r = 0; r < 4; ++r) acc[0][r] = bj;
    };

    // GEMM over one K-half: A = st (f16 LDS), B = W rows [half*128, +128)
    // layer: 0 -> W2, 1 -> W3
    auto gemm_half = [&](const float* __restrict__ W, int layer, int half) {
#pragma unroll
        for (int ks = 0; ks < 4; ++ks) {
            const int kg = half * KH + ks * 32 + q * 8;
            half8 bf;
            if constexpr (TW) {
                bf = *(const half8*)&Wt[(layer * HDIM + j) * HDIM + kg];
            } else {
#pragma unroll
                for (int i = 0; i < 8; ++i) bf[i] = (_Float16)W[(kg + i) * HDIM + j];
            }
#pragma unroll
            for (int mt = 0; mt < NC; ++mt) {
                half8 af = *(const half8*)&st[(mt * 16 + col) * STRIDE + ks * 32 + q * 8];
                acc[mt] = __builtin_amdgcn_mfma_f32_16x16x32_f16(af, bf, acc[mt], 0, 0, 0);
            }
        }
    };

    // tanh chain rule on acc -> hold (f16)
    auto transform_hold = [&]() {
#pragma unroll
        for (int r = 0; r < 4; ++r) {
            float pre[NC];
#pragma unroll
            for (int c = 0; c < NC; ++c) pre[c] = acc[c][r];
            float v = tanhf(pre[0]), tp = 1.f - v * v, m2 = -2.f * v * tp;
            float g[4] = {pre[1], pre[2], pre[3], pre[4]};
            hold[0 * 4 + r] = (_Float16)v;
#pragma unroll
            for (int k = 0; k < 4; ++k) hold[(1 + k) * 4 + r] = (_Float16)(tp * g[k]);
            int idx = 5;
#pragma unroll
            for (int aa = 0; aa < 4; ++aa)
#pragma unroll
                for (int bb2 = aa; bb2 < 4; ++bb2) {
                    hold[idx * 4 + r] = (_Float16)fmaf(tp, pre[idx], m2 * g[aa] * g[bb2]);
                    ++idx;
                }
        }
    };

    auto store_hold = [&](int half) {
        const int jl = j - half * KH;            // in [0,128)
#pragma unroll
        for (int c = 0; c < NC; ++c)
#pragma unroll
            for (int r = 0; r < 4; ++r)
                st[(c * 16 + q * 4 + r) * STRIDE + jl] = hold[c * 4 + r];
    };

    // ================= pipeline =================
    produce1(0);
    __syncthreads();
    init_acc(b2);
    gemm_half(W2, 0, 0);
    __syncthreads();
    produce1(1);
    __syncthreads();
    gemm_half(W2, 0, 1);
    __syncthreads();                  // layer-1 state fully consumed
    transform_hold();                 // layer-2 state (f16, regs)
    if (w < 8) store_hold(0);         // waves owning j<128
    __syncthreads();
    init_acc(b3);
    gemm_half(W3, 1, 0);
    __syncthreads();
    if (w >= 8) store_hold(1);
    __syncthreads();
    gemm_half(W3, 1, 1);

    // ---- layer-3 tanh chain + output dot with Wo ----
    float p[NC][4];
    {
        float wo = Wo[j];
#pragma unroll
        for (int r = 0; r < 4; ++r) {
            float pre[NC];
#pragma unroll
            for (int c = 0; c < NC; ++c) pre[c] = acc[c][r];
            float v = tanhf(pre[0]), tp = 1.f - v * v, m2 = -2.f * v * tp;
            float g[4] = {pre[1], pre[2], pre[3], pre[4]};
            p[0][r] = wo * v;
#pragma unroll
            for (int k = 0; k < 4; ++k) p[1 + k][r] = wo * tp * g[k];
            int idx = 5;
#pragma unroll
            for (int aa = 0; aa < 4; ++aa)
#pragma unroll
                for (int bb2 = aa; bb2 < 4; ++bb2) {
                    p[idx][r] = wo * fmaf(tp, pre[idx], m2 * g[aa] * g[bb2]);
                    ++idx;
                }
        }
    }
    // reduce over the 16 col-lanes (neurons within wave)
#pragma unroll
    for (int mask = 1; mask < 16; mask <<= 1)
#pragma unroll
        for (int c = 0; c < NC; ++c)
#pragma unroll
            for (int r = 0; r < 4; ++r)
                p[c][r] += __shfl_xor(p[c][r], mask, 64);

    __syncthreads();                  // all st reads done; safe to alias
    float* part = (float*)st;         // [0, 3840) floats: part[w][c][sl]
    float* fin  = ((float*)st) + 4096;// [4096, 4352): fin[sl][c]
    if (col == 0) {
#pragma unroll
        for (int c = 0; c < NC; ++c)
#pragma unroll
            for (int r = 0; r < 4; ++r)
                part[w * MROWS + c * 16 + q * 4 + r] = p[c][r];
    }
    __syncthreads();
    if (tid < MROWS) {
        float v = 0.f;
#pragma unroll
        for (int ww = 0; ww < 16; ++ww) v += part[ww * MROWS + tid];
        int c = tid >> 4, sl = tid & 15;
        if (c == 0) v += bo[0];
        fin[sl * 16 + c] = v;
    }
    __syncthreads();
    if (tid < SPB) {
        int s = s0 + tid;
        if (s < B) {
            float f = fin[tid * 16 + 0];
            float Gf[4], Hs[10];
#pragma unroll
            for (int k = 0; k < 4; ++k) Gf[k] = fin[tid * 16 + 1 + k];
#pragma unroll
            for (int qq = 0; qq < 10; ++qq) Hs[qq] = fin[tid * 16 + 5 + qq];
            float r  = coords[s * 4 + 1];
            float th = coords[s * 4 + 2];
            float res[16];
            einstein_tail(f, Gf, Hs, r, th, res);
#pragma unroll
            for (int e = 0; e < 16; ++e) out[s * 16 + e] = res[e];
        }
    }
}

extern "C" void kernel_launch(void* const* d_in, const int* in_sizes, int n_in,
                              void* d_out, int out_size, void* d_ws, size_t ws_size,
                              hipStream_t stream) {
    const float* coords = (const float*)d_in[0];
    const float* W1 = (const float*)d_in[1];
    const float* b1 = (const float*)d_in[2];
    const float* W2 = (const float*)d_in[3];
    const float* b2 = (const float*)d_in[4];
    const float* W3 = (const float*)d_in[5];
    const float* b3 = (const float*)d_in[6];
    const float* Wo = (const float*)d_in[7];
    const float* bo = (const float*)d_in[8];
    float* out = (float*)d_out;
    const int B = in_sizes[0] / 4;
    const int nblocks = (B + SPB - 1) / SPB;

    const size_t wt_bytes = (size_t)2 * HDIM * HDIM * sizeof(_Float16);
    if (ws_size >= wt_bytes) {
        _Float16* Wt = (_Float16*)d_ws;
        pack_wt<<<(2 * HDIM * HDIM) / 256, 256, 0, stream>>>(W2, W3, Wt);
        mlp_fused<true><<<nblocks, 1024, 0, stream>>>(
            coords, W1, b1, W2, b2, W3, b3, Wo, bo, Wt, out, B);
    } else {
        mlp_fused<false><<<nblocks, 1024, 0, stream>>>(
            coords, W1, b1, W2, b2, W3, b3, Wo, bo, nullptr, out, B);
    }
}